// Round 8
// baseline (123.129 us; speedup 1.0000x reference)
//
#include <hip/hip_runtime.h>
#include <hip/hip_bf16.h>

// Problem: B=4, S=2048, D=512, H=8, HD=64
#define B_ 4
#define S_ 2048
#define D_ 512
#define H_ 8
#define HD_ 64

typedef unsigned int uint;
typedef unsigned short ushort_t;
typedef __attribute__((ext_vector_type(4))) float f32x4;
typedef __attribute__((ext_vector_type(16))) float f32x16;
typedef __attribute__((ext_vector_type(8))) short bf16x8;

#if __has_builtin(__builtin_amdgcn_exp2f)
#define EXP2F __builtin_amdgcn_exp2f
#else
#define EXP2F exp2f
#endif

__device__ __forceinline__ float bf2f(unsigned short u){ union{uint i;float f;}c; c.i = (uint)u<<16; return c.f; }
__device__ __forceinline__ unsigned short f2bf(float f){
    __hip_bfloat16 h = __float2bfloat16(f);
    return *reinterpret_cast<unsigned short*>(&h);
}

__device__ __forceinline__ void gload16(const unsigned short* g, const ushort_t* l){
    __builtin_amdgcn_global_load_lds(
        (const __attribute__((address_space(1))) unsigned int*)g,
        (__attribute__((address_space(3))) unsigned int*)l, 16, 0, 0);
}

// ---------------------------------------------------------------------------
// Kernel 0: fp32 -> bf16 conversion of x, [Wq;Wk;Wv], Wo; plus mask->bias.
// ---------------------------------------------------------------------------
__global__ __launch_bounds__(256) void convert_all(
    const float* __restrict__ x,
    const float* __restrict__ Wq, const float* __restrict__ Wk,
    const float* __restrict__ Wv, const float* __restrict__ Wo,
    const int* __restrict__ mask,
    ushort_t* __restrict__ xb, ushort_t* __restrict__ Wqkvb, ushort_t* __restrict__ Wob,
    float* __restrict__ mbg)
{
    const int NX = 1048576;            // x in float4 units (8192*512/4)
    const int NW = 65536;              // one W in float4 units
    const int total = NX + 4 * NW;     // 1310720
    for (int i = blockIdx.x * 256 + threadIdx.x; i < total; i += gridDim.x * 256) {
        const float* src; ushort_t* dst; int so, dofs;
        if (i < NX) { src = x; so = i; dst = xb; dofs = i; }
        else if (i < NX + 3 * NW) {
            int j = i - NX;
            if (j < NW)          { src = Wq; so = j; }
            else if (j < 2 * NW) { src = Wk; so = j - NW; }
            else                 { src = Wv; so = j - 2 * NW; }
            dst = Wqkvb; dofs = j;
        } else { int k = i - NX - 3 * NW; src = Wo; so = k; dst = Wob; dofs = k; }
        float4 v = ((const float4*)src)[so];
        ushort4 u;
        u.x = f2bf(v.x); u.y = f2bf(v.y); u.z = f2bf(v.z); u.w = f2bf(v.w);
        ((ushort4*)dst)[dofs] = u;
    }
    // mask bias: 8192 ints -> 2048 int4
    for (int i = blockIdx.x * 256 + threadIdx.x; i < 2048; i += gridDim.x * 256) {
        int4 mv = ((const int4*)mask)[i];
        float4 o;
        o.x = mv.x ? 0.f : -1e30f;
        o.y = mv.y ? 0.f : -1e30f;
        o.z = mv.z ? 0.f : -1e30f;
        o.w = mv.w ? 0.f : -1e30f;
        ((float4*)mbg)[i] = o;
    }
}

// ---------------------------------------------------------------------------
// bf16 MFMA GEMM, m97 structure (unchanged).
// ---------------------------------------------------------------------------
template<int MODE>
__global__ __launch_bounds__(256) void gemm_mfma(
    const ushort_t* __restrict__ A, const ushort_t* __restrict__ Bw,
    const float* __restrict__ b0, const float* __restrict__ b1, const float* __restrict__ b2,
    ushort_t* __restrict__ O0, ushort_t* __restrict__ O1, ushort_t* __restrict__ O2,
    float* __restrict__ Of)
{
    __shared__ __align__(16) unsigned char smem[34816];
    ushort_t* sA = (ushort_t*)smem;          // [128][64]
    ushort_t* sB = sA + 8192;                // [128][64]

    const int t = threadIdx.x, w = t >> 6, l = t & 63, g = l >> 4, c = l & 15;
    const int wm = w >> 1, wn = w & 1;
    const int row0 = blockIdx.y * 128, col0 = blockIdx.x * 128;

    const ushort_t* aSrc[4]; const ushort_t* bSrc[4];
    ushort_t* aDst[4]; ushort_t* bDst[4];
    #pragma unroll
    for (int i = 0; i < 4; ++i) {
        int cc = i * 256 + t;
        int row = cc >> 3, slot = (cc & 7) ^ (row & 7);
        aSrc[i] = A  + (size_t)(row0 + row) * 512 + slot * 8;
        bSrc[i] = Bw + (size_t)(col0 + row) * 512 + slot * 8;
        aDst[i] = sA + (i * 256 + w * 64) * 8;
        bDst[i] = sB + (i * 256 + w * 64) * 8;
    }

    f32x4 acc[4][4];
    #pragma unroll
    for (int mi = 0; mi < 4; ++mi)
        #pragma unroll
        for (int ni = 0; ni < 4; ++ni) acc[mi][ni] = (f32x4)0.f;

    for (int ks = 0; ks < 8; ++ks) {
        #pragma unroll
        for (int i = 0; i < 4; ++i) {
            gload16(aSrc[i], aDst[i]);
            gload16(bSrc[i], bDst[i]);
        }
        __syncthreads();
        #pragma unroll
        for (int kh = 0; kh < 2; ++kh) {
            bf16x8 af[4], bfv[4];
            const int sw = (((kh << 2) | g) ^ (c & 7)) << 3;
            #pragma unroll
            for (int mi = 0; mi < 4; ++mi)
                af[mi] = *(const bf16x8*)&sA[(wm * 64 + mi * 16 + c) * 64 + sw];
            #pragma unroll
            for (int ni = 0; ni < 4; ++ni)
                bfv[ni] = *(const bf16x8*)&sB[(wn * 64 + ni * 16 + c) * 64 + sw];
            #pragma unroll
            for (int mi = 0; mi < 4; ++mi)
                #pragma unroll
                for (int ni = 0; ni < 4; ++ni)
                    acc[mi][ni] = __builtin_amdgcn_mfma_f32_16x16x32_bf16(af[mi], bfv[ni], acc[mi][ni], 0, 0, 0);
        }
        #pragma unroll
        for (int i = 0; i < 4; ++i) { aSrc[i] += 64; bSrc[i] += 64; }
        __syncthreads();
    }

    if (MODE == 1) {
        #pragma unroll
        for (int mi = 0; mi < 4; ++mi)
            #pragma unroll
            for (int ni = 0; ni < 4; ++ni) {
                int n = col0 + wn * 64 + ni * 16 + c;
                float bias = b0[n];
                #pragma unroll
                for (int r = 0; r < 4; ++r)
                    Of[(size_t)(row0 + wm * 64 + mi * 16 + 4 * g + r) * 512 + n] =
                        acc[mi][ni][r] + bias;
            }
    } else {
        const int which = col0 >> 9;   // 0=Q 1=K 2=V
        const float* bias = which == 0 ? b0 : (which == 1 ? b1 : b2);
        ushort_t (*Cl)[136] = (ushort_t(*)[136])smem;
        if (which < 2) {
            #pragma unroll
            for (int mi = 0; mi < 4; ++mi)
                #pragma unroll
                for (int ni = 0; ni < 4; ++ni) {
                    int n = wn * 64 + ni * 16 + c;
                    float bb = bias[(col0 & 511) + n];
                    #pragma unroll
                    for (int r = 0; r < 4; ++r)
                        Cl[wm * 64 + mi * 16 + 4 * g + r][n] = f2bf(acc[mi][ni][r] + bb);
                }
        } else {
            #pragma unroll
            for (int mi = 0; mi < 4; ++mi)
                #pragma unroll
                for (int ni = 0; ni < 4; ++ni) {
                    int n = wn * 64 + ni * 16 + c;
                    float bb = bias[(col0 & 511) + n];
                    #pragma unroll
                    for (int r = 0; r < 4; ++r)
                        Cl[n][wm * 64 + mi * 16 + 4 * g + r] = f2bf(acc[mi][ni][r] + bb);
                }
        }
        __syncthreads();
        const int r = t >> 1, half = t & 1;
        const int b = row0 >> 11;
        if (which < 2) {
            ushort_t* Out = which == 0 ? O0 : O1;
            int s = (row0 & 2047) + r;
            int e = (col0 & 511) + half * 64;
            int h = e >> 6;
            ushort_t* dst = Out + (((size_t)(b * 8 + h) * 2048 + s) << 6);
            #pragma unroll
            for (int j = 0; j < 8; ++j)
                *(bf16x8*)(dst + j * 8) = *(const bf16x8*)&Cl[r][half * 64 + j * 8];
        } else {
            int e = (col0 & 511) + r;
            int h = e >> 6, d = e & 63;
            int s0 = (row0 & 2047) + half * 64;
            ushort_t* dst = O2 + ((size_t)(b * 8 + h) * 64 + d) * 2048 + s0;
            #pragma unroll
            for (int j = 0; j < 8; ++j)
                *(bf16x8*)(dst + j * 8) = *(const bf16x8*)&Cl[r][half * 64 + j * 8];
        }
    }
}

// ---------------------------------------------------------------------------
// Vsum[b,h,d] = sum_s V[b,h,s,d] from Vt rows (coalesced).
// ---------------------------------------------------------------------------
__global__ __launch_bounds__(256) void vsum2(
    const __hip_bfloat16* __restrict__ Vt, float* __restrict__ Vsum)
{
    const int row = blockIdx.x * 4 + (threadIdx.x >> 6);   // 0..2047 = bh*64+d
    const int l = threadIdx.x & 63;
    const unsigned short* p = (const unsigned short*)Vt + (size_t)row * S_;
    float s = 0.f;
    #pragma unroll
    for (int i = 0; i < 4; ++i) {
        uint4 u = *(const uint4*)(p + i * 512 + l * 8);
        s += bf2f((unsigned short)(u.x & 0xffff)) + bf2f((unsigned short)(u.x >> 16));
        s += bf2f((unsigned short)(u.y & 0xffff)) + bf2f((unsigned short)(u.y >> 16));
        s += bf2f((unsigned short)(u.z & 0xffff)) + bf2f((unsigned short)(u.z >> 16));
        s += bf2f((unsigned short)(u.w & 0xffff)) + bf2f((unsigned short)(u.w >> 16));
    }
    #pragma unroll
    for (int m = 1; m < 64; m <<= 1) s += __shfl_xor(s, m);
    if (l == 0) Vsum[row] = s;
}

// ---------------------------------------------------------------------------
// MFMA flash attention, round 8: 32x32x16, register-P (phi trick, r7-proven),
// 64 q/wave, 8B-granule LDS swizzle (2-way max = free), reg-staged K/V tiles
// (T14 split: global loads at step top, swizzled ds_write_b64 after compute).
// Grid 256 = 1 block/CU, 4 waves (1/SIMD), launch_bounds(256,1) frees VGPRs.
// ---------------------------------------------------------------------------
__global__ __launch_bounds__(256, 1) void attn_mfma(
    const __hip_bfloat16* __restrict__ Qb, const __hip_bfloat16* __restrict__ Kb,
    const __hip_bfloat16* __restrict__ Vt, const float* __restrict__ Vsum,
    const float* __restrict__ dock, const int* __restrict__ mask,
    const float* __restrict__ mbg, const float* __restrict__ beta_p,
    ushort_t* __restrict__ ctxb)
{
    __shared__ __align__(16) unsigned char smem[36864];
    ushort_t* Kbuf = (ushort_t*)smem;                 // [2][64][64] ush = 16 KB
    ushort_t* Vbuf = (ushort_t*)(smem + 16384);       // [2][64][64] ush = 16 KB
    // epilogue alias: ushort [4][64][72] = 36864 B

    // XCD swizzle: 4 bh per XCD, 8 qtiles (256 q) per bh.
    const int flat = blockIdx.x;
    const int xcd = flat & 7, idx = flat >> 3;        // idx 0..31
    const int bh = ((idx >> 3) << 3) | xcd;
    const int qtile = idx & 7;
    const int b = bh >> 3, h8 = bh & 7;
    const int t = threadIdx.x, w = t >> 6, lam = t & 63;
    const int lq = lam & 31, hf = lam >> 5;
    const int q0 = qtile * 256 + w * 64;
    const float beta = beta_p[0];
    const ushort_t* Kp = (const ushort_t*)Kb + (size_t)bh * S_ * HD_;
    const ushort_t* Vp = (const ushort_t*)Vt + (size_t)bh * HD_ * S_;
    const float* mbp = mbg + b * S_;

    // staging thread geometry: row = t>>2 (0..63), quad = t&3; conflict-free
    const int srow = t >> 2, squad = t & 3;
    const int sx = ((srow & 7) << 1) | ((srow >> 3) & 1);
    int wof[4];
    #pragma unroll
    for (int i = 0; i < 4; ++i)
        wof[i] = srow * 64 + ((((squad << 2) | i) ^ sx) << 2);

    // frag-read swizzle (same for K rows kt2*32+lq and V rows dt*32+lq)
    const int xr = ((lq & 7) << 1) | ((lq >> 3) & 1);

    // Q fragments: qf[qt2][hd] = Q[q0+qt2*32+lq][hd*16 + hf*8 + 0..7]
    bf16x8 qf[2][4];
    #pragma unroll
    for (int qt2 = 0; qt2 < 2; ++qt2)
        #pragma unroll
        for (int hd = 0; hd < 4; ++hd)
            qf[qt2][hd] = *(const bf16x8*)((const ushort_t*)Qb +
                ((size_t)bh * S_ + q0 + qt2 * 32 + lq) * HD_ + hd * 16 + hf * 8);

    f32x16 cacc[2][2];   // [qt2][dt]
    cacc[0][0] = (f32x16)0.f; cacc[0][1] = (f32x16)0.f;
    cacc[1][0] = (f32x16)0.f; cacc[1][1] = (f32x16)0.f;
    float l_[2] = {0.f, 0.f};
    const float CSC = 0.18033688011112042f;   // 0.125 * log2(e)

    // ---- prologue: stage tile 0 into par 0 ----
    {
        uint4 kg0 = *(const uint4*)(Kp + (size_t)srow * 64 + squad * 16);
        uint4 kg1 = *(const uint4*)(Kp + (size_t)srow * 64 + squad * 16 + 8);
        uint4 vg0 = *(const uint4*)(Vp + (size_t)srow * 2048 + squad * 16);
        uint4 vg1 = *(const uint4*)(Vp + (size_t)srow * 2048 + squad * 16 + 8);
        *(uint2*)(Kbuf + wof[0]) = make_uint2(kg0.x, kg0.y);
        *(uint2*)(Kbuf + wof[1]) = make_uint2(kg0.z, kg0.w);
        *(uint2*)(Kbuf + wof[2]) = make_uint2(kg1.x, kg1.y);
        *(uint2*)(Kbuf + wof[3]) = make_uint2(kg1.z, kg1.w);
        *(uint2*)(Vbuf + wof[0]) = make_uint2(vg0.x, vg0.y);
        *(uint2*)(Vbuf + wof[1]) = make_uint2(vg0.z, vg0.w);
        *(uint2*)(Vbuf + wof[2]) = make_uint2(vg1.x, vg1.y);
        *(uint2*)(Vbuf + wof[3]) = make_uint2(vg1.z, vg1.w);
    }
    __syncthreads();

    for (int k0 = 0; k0 < S_; k0 += 64) {
        const int par = (k0 >> 6) & 1;
        const ushort_t* KBp = Kbuf + par * 4096;
        const ushort_t* VBp = Vbuf + par * 4096;
        const bool pre = (k0 + 64 < S_);

        // (1) issue next-tile global loads — in flight under this step's compute
        uint4 kg0, kg1, vg0, vg1;
        if (pre) {
            kg0 = *(const uint4*)(Kp + (size_t)(k0 + 64 + srow) * 64 + squad * 16);
            kg1 = *(const uint4*)(Kp + (size_t)(k0 + 64 + srow) * 64 + squad * 16 + 8);
            vg0 = *(const uint4*)(Vp + (size_t)srow * 2048 + k0 + 64 + squad * 16);
            vg1 = *(const uint4*)(Vp + (size_t)srow * 2048 + k0 + 64 + squad * 16 + 8);
        }
        // (2) mask-bias for this step's 64 keys (L1-resident, broadcast)
        float4 mb[2][4];
        #pragma unroll
        for (int kt2 = 0; kt2 < 2; ++kt2)
            #pragma unroll
            for (int qd = 0; qd < 4; ++qd)
                mb[kt2][qd] = *(const float4*)(mbp + k0 + kt2 * 32 + qd * 8 + hf * 4);

        // (3) QK^T: sacc[qt2][kt2], D[key][q]
        f32x16 sacc[2][2];
        sacc[0][0] = (f32x16)0.f; sacc[0][1] = (f32x16)0.f;
        sacc[1][0] = (f32x16)0.f; sacc[1][1] = (f32x16)0.f;
        __builtin_amdgcn_s_setprio(1);
        #pragma unroll
        for (int kt2 = 0; kt2 < 2; ++kt2) {
            const ushort_t* kr = KBp + (kt2 * 32 + lq) * 64;
            #pragma unroll
            for (int hd = 0; hd < 4; ++hd) {
                uint2 lo = *(const uint2*)(kr + ((((hd << 2) | (hf << 1)) ^ xr) << 2));
                uint2 hi = *(const uint2*)(kr + ((((hd << 2) | (hf << 1) | 1) ^ xr) << 2));
                union { bf16x8 v; uint4 u; } kf;
                kf.u = make_uint4(lo.x, lo.y, hi.x, hi.y);
                sacc[0][kt2] = __builtin_amdgcn_mfma_f32_32x32x16_bf16(kf.v, qf[0][hd], sacc[0][kt2], 0, 0, 0);
                sacc[1][kt2] = __builtin_amdgcn_mfma_f32_32x32x16_bf16(kf.v, qf[1][hd], sacc[1][kt2], 0, 0, 0);
            }
        }
        __builtin_amdgcn_s_setprio(0);

        // (4) softmax numerator (no max; scores provably tiny)
        float p[2][2][16];
        #pragma unroll
        for (int qt2 = 0; qt2 < 2; ++qt2) {
            float ps = 0.f;
            #pragma unroll
            for (int kt2 = 0; kt2 < 2; ++kt2)
                #pragma unroll
                for (int qd = 0; qd < 4; ++qd) {
                    float4 m4 = mb[kt2][qd];
                    float p0 = EXP2F(fmaf(sacc[qt2][kt2][qd * 4 + 0], CSC, m4.x));
                    float p1 = EXP2F(fmaf(sacc[qt2][kt2][qd * 4 + 1], CSC, m4.y));
                    float p2 = EXP2F(fmaf(sacc[qt2][kt2][qd * 4 + 2], CSC, m4.z));
                    float p3 = EXP2F(fmaf(sacc[qt2][kt2][qd * 4 + 3], CSC, m4.w));
                    p[qt2][kt2][qd * 4 + 0] = p0; p[qt2][kt2][qd * 4 + 1] = p1;
                    p[qt2][kt2][qd * 4 + 2] = p2; p[qt2][kt2][qd * 4 + 3] = p3;
                    ps += p0 + p1 + p2 + p3;
                }
            l_[qt2] += ps;
        }

        // (5) PV: B-frag = own p regs (phi), A-frag = V b64 pair; V reused x2 qt2
        __builtin_amdgcn_s_setprio(1);
        #pragma unroll
        for (int kt2 = 0; kt2 < 2; ++kt2)
            #pragma unroll
            for (int ks = 0; ks < 2; ++ks) {
                bf16x8 pf0, pf1;
                #pragma unroll
                for (int m = 0; m < 8; ++m) {
                    pf0[m] = (short)f2bf(p[0][kt2][ks * 8 + m]);
                    pf1[m] = (short)f2bf(p[1][kt2][ks * 8 + m]);
                }
                #pragma unroll
                for (int dt = 0; dt < 2; ++dt) {
                    const ushort_t* vr = VBp + (dt * 32 + lq) * 64;
                    uint2 lo = *(const uint2*)(vr + (((8 * kt2 + 4 * ks + hf) ^ xr) << 2));
                    uint2 hi = *(const uint2*)(vr + (((8 * kt2 + 4 * ks + 2 + hf) ^ xr) << 2));
                    union { bf16x8 v; uint4 u; } vf;
                    vf.u = make_uint4(lo.x, lo.y, hi.x, hi.y);
                    cacc[0][dt] = __builtin_amdgcn_mfma_f32_32x32x16_bf16(vf.v, pf0, cacc[0][dt], 0, 0, 0);
                    cacc[1][dt] = __builtin_amdgcn_mfma_f32_32x32x16_bf16(vf.v, pf1, cacc[1][dt], 0, 0, 0);
                }
            }
        __builtin_amdgcn_s_setprio(0);

        // (6) commit next tile (compiler inserts vmcnt before first use)
        if (pre) {
            ushort_t* KD = Kbuf + (par ^ 1) * 4096;
            ushort_t* VD = Vbuf + (par ^ 1) * 4096;
            *(uint2*)(KD + wof[0]) = make_uint2(kg0.x, kg0.y);
            *(uint2*)(KD + wof[1]) = make_uint2(kg0.z, kg0.w);
            *(uint2*)(KD + wof[2]) = make_uint2(kg1.x, kg1.y);
            *(uint2*)(KD + wof[3]) = make_uint2(kg1.z, kg1.w);
            *(uint2*)(VD + wof[0]) = make_uint2(vg0.x, vg0.y);
            *(uint2*)(VD + wof[1]) = make_uint2(vg0.z, vg0.w);
            *(uint2*)(VD + wof[2]) = make_uint2(vg1.x, vg1.y);
            *(uint2*)(VD + wof[3]) = make_uint2(vg1.z, vg1.w);
        }
        __syncthreads();
    }

    // finalize l: complementary 16-key half lives in lane^32
    l_[0] += __shfl_xor(l_[0], 32);
    l_[1] += __shfl_xor(l_[1], 32);

    __syncthreads();   // staging buffers dead -> reuse as ctxl

    // ---- epilogue: blend + transpose via LDS (bf16), coalesced-ish writes ----
    ushort_t* ctxl = (ushort_t*)smem;   // [4][64][72]
    #pragma unroll
    for (int qt2 = 0; qt2 < 2; ++qt2) {
        const int qg = q0 + qt2 * 32 + lq;
        const float w1 = (1.f - beta) / l_[qt2];
        const float dq = (mask[b * S_ + qg] ? dock[b * S_ + qg] : 0.f) * beta;
        #pragma unroll
        for (int dt = 0; dt < 2; ++dt)
            #pragma unroll
            for (int qd = 0; qd < 4; ++qd) {
                const int d0 = dt * 32 + qd * 8 + hf * 4;
                float4 vs = *(const float4*)(Vsum + bh * 64 + d0);
                float o0 = cacc[qt2][dt][qd * 4 + 0] * w1 + dq * vs.x;
                float o1 = cacc[qt2][dt][qd * 4 + 1] * w1 + dq * vs.y;
                float o2 = cacc[qt2][dt][qd * 4 + 2] * w1 + dq * vs.z;
                float o3 = cacc[qt2][dt][qd * 4 + 3] * w1 + dq * vs.w;
                uint lo = (uint)f2bf(o0) | ((uint)f2bf(o1) << 16);
                uint hi = (uint)f2bf(o2) | ((uint)f2bf(o3) << 16);
                *(uint2*)(ctxl + (size_t)w * 4608 + (qt2 * 32 + lq) * 72 + d0) =
                    make_uint2(lo, hi);
            }
    }
    __syncthreads();
    {
        ushort_t* cp = ctxb + ((size_t)(b * 2048 + q0 + lam)) * 512 + h8 * 64;
        const ushort_t* rp = ctxl + (size_t)w * 4608 + lam * 72;
        #pragma unroll
        for (int j = 0; j < 8; ++j)
            *(bf16x8*)(cp + j * 8) = *(const bf16x8*)(rp + j * 8);
    }
}

extern "C" void kernel_launch(void* const* d_in, const int* in_sizes, int n_in,
                              void* d_out, int out_size, void* d_ws, size_t ws_size,
                              hipStream_t stream)
{
    const float* x    = (const float*)d_in[0];
    const float* dock = (const float*)d_in[1];
    const int*   mask = (const int*)d_in[2];
    const float* Wq   = (const float*)d_in[3];
    const float* bq   = (const float*)d_in[4];
    const float* Wk   = (const float*)d_in[5];
    const float* bk   = (const float*)d_in[6];
    const float* Wv   = (const float*)d_in[7];
    const float* bv   = (const float*)d_in[8];
    const float* Wo   = (const float*)d_in[9];
    const float* bo   = (const float*)d_in[10];
    const float* beta = (const float*)d_in[12];   // alpha = d_in[11] unused
    float* out = (float*)d_out;

    const size_t nqkv = (size_t)B_ * H_ * S_ * HD_;   // 4,194,304 elems
    ushort_t* xb    = (ushort_t*)d_ws;                // 8 MB (reused as ctxb)
    ushort_t* Qb    = xb + nqkv;                      // 8 MB
    ushort_t* Kb    = Qb + nqkv;                      // 8 MB
    ushort_t* Vt    = Kb + nqkv;                      // 8 MB (B,H,HD,S)
    ushort_t* Wqkvb = Vt + nqkv;                      // 1.5 MB  [1536][512]
    ushort_t* Wob   = Wqkvb + 1536 * 512;             // 0.5 MB  [512][512]
    float*    Vsum  = (float*)(Wob + 512 * 512);      // 8 KB
    float*    mbg   = Vsum + 2048;                    // 32 KB mask-bias
    ushort_t* ctxb  = xb;                             // alias (x consumed by then)

    convert_all<<<1280, 256, 0, stream>>>(x, Wq, Wk, Wv, Wo, mask, xb, Wqkvb, Wob, mbg);
    gemm_mfma<0><<<dim3(12, 64), 256, 0, stream>>>(xb, Wqkvb, bq, bk, bv, Qb, Kb, Vt, nullptr);
    vsum2<<<512, 256, 0, stream>>>((const __hip_bfloat16*)Vt, Vsum);
    attn_mfma<<<256, 256, 0, stream>>>(
        (const __hip_bfloat16*)Qb, (const __hip_bfloat16*)Kb, (const __hip_bfloat16*)Vt,
        Vsum, dock, mask, mbg, beta, ctxb);
    gemm_mfma<1><<<dim3(4, 64), 256, 0, stream>>>(ctxb, Wob, bo, nullptr, nullptr,
                                                  nullptr, nullptr, nullptr, out);
}

// Round 9
// 108.402 us; speedup vs baseline: 1.1359x; 1.1359x over previous
//
#include <hip/hip_runtime.h>
#include <hip/hip_bf16.h>

// Problem: B=4, S=2048, D=512, H=8, HD=64
#define B_ 4
#define S_ 2048
#define D_ 512
#define H_ 8
#define HD_ 64

typedef unsigned int uint;
typedef unsigned short ushort_t;
typedef __attribute__((ext_vector_type(4))) float f32x4;
typedef __attribute__((ext_vector_type(16))) float f32x16;
typedef __attribute__((ext_vector_type(8))) short bf16x8;

#if __has_builtin(__builtin_amdgcn_exp2f)
#define EXP2F __builtin_amdgcn_exp2f
#else
#define EXP2F exp2f
#endif

__device__ __forceinline__ float bf2f(unsigned short u){ union{uint i;float f;}c; c.i = (uint)u<<16; return c.f; }
__device__ __forceinline__ unsigned short f2bf(float f){
    __hip_bfloat16 h = __float2bfloat16(f);
    return *reinterpret_cast<unsigned short*>(&h);
}

__device__ __forceinline__ void gload16(const unsigned short* g, const ushort_t* l){
    __builtin_amdgcn_global_load_lds(
        (const __attribute__((address_space(1))) unsigned int*)g,
        (__attribute__((address_space(3))) unsigned int*)l, 16, 0, 0);
}

// ---------------------------------------------------------------------------
// Kernel 0: fp32 -> bf16 conversion of x, [Wq;Wk;Wv], Wo; plus mask->bias.
// ---------------------------------------------------------------------------
__global__ __launch_bounds__(256) void convert_all(
    const float* __restrict__ x,
    const float* __restrict__ Wq, const float* __restrict__ Wk,
    const float* __restrict__ Wv, const float* __restrict__ Wo,
    const int* __restrict__ mask,
    ushort_t* __restrict__ xb, ushort_t* __restrict__ Wqkvb, ushort_t* __restrict__ Wob,
    float* __restrict__ mbg)
{
    const int NX = 1048576;            // x in float4 units (8192*512/4)
    const int NW = 65536;              // one W in float4 units
    const int total = NX + 4 * NW;     // 1310720
    for (int i = blockIdx.x * 256 + threadIdx.x; i < total; i += gridDim.x * 256) {
        const float* src; ushort_t* dst; int so, dofs;
        if (i < NX) { src = x; so = i; dst = xb; dofs = i; }
        else if (i < NX + 3 * NW) {
            int j = i - NX;
            if (j < NW)          { src = Wq; so = j; }
            else if (j < 2 * NW) { src = Wk; so = j - NW; }
            else                 { src = Wv; so = j - 2 * NW; }
            dst = Wqkvb; dofs = j;
        } else { int k = i - NX - 3 * NW; src = Wo; so = k; dst = Wob; dofs = k; }
        float4 v = ((const float4*)src)[so];
        ushort4 u;
        u.x = f2bf(v.x); u.y = f2bf(v.y); u.z = f2bf(v.z); u.w = f2bf(v.w);
        ((ushort4*)dst)[dofs] = u;
    }
    // mask bias: 8192 ints -> 2048 int4
    for (int i = blockIdx.x * 256 + threadIdx.x; i < 2048; i += gridDim.x * 256) {
        int4 mv = ((const int4*)mask)[i];
        float4 o;
        o.x = mv.x ? 0.f : -1e30f;
        o.y = mv.y ? 0.f : -1e30f;
        o.z = mv.z ? 0.f : -1e30f;
        o.w = mv.w ? 0.f : -1e30f;
        ((float4*)mbg)[i] = o;
    }
}

// ---------------------------------------------------------------------------
// bf16 MFMA GEMM, m97 structure (unchanged).
// ---------------------------------------------------------------------------
template<int MODE>
__global__ __launch_bounds__(256) void gemm_mfma(
    const ushort_t* __restrict__ A, const ushort_t* __restrict__ Bw,
    const float* __restrict__ b0, const float* __restrict__ b1, const float* __restrict__ b2,
    ushort_t* __restrict__ O0, ushort_t* __restrict__ O1, ushort_t* __restrict__ O2,
    float* __restrict__ Of)
{
    __shared__ __align__(16) unsigned char smem[34816];
    ushort_t* sA = (ushort_t*)smem;          // [128][64]
    ushort_t* sB = sA + 8192;                // [128][64]

    const int t = threadIdx.x, w = t >> 6, l = t & 63, g = l >> 4, c = l & 15;
    const int wm = w >> 1, wn = w & 1;
    const int row0 = blockIdx.y * 128, col0 = blockIdx.x * 128;

    const ushort_t* aSrc[4]; const ushort_t* bSrc[4];
    ushort_t* aDst[4]; ushort_t* bDst[4];
    #pragma unroll
    for (int i = 0; i < 4; ++i) {
        int cc = i * 256 + t;
        int row = cc >> 3, slot = (cc & 7) ^ (row & 7);
        aSrc[i] = A  + (size_t)(row0 + row) * 512 + slot * 8;
        bSrc[i] = Bw + (size_t)(col0 + row) * 512 + slot * 8;
        aDst[i] = sA + (i * 256 + w * 64) * 8;
        bDst[i] = sB + (i * 256 + w * 64) * 8;
    }

    f32x4 acc[4][4];
    #pragma unroll
    for (int mi = 0; mi < 4; ++mi)
        #pragma unroll
        for (int ni = 0; ni < 4; ++ni) acc[mi][ni] = (f32x4)0.f;

    for (int ks = 0; ks < 8; ++ks) {
        #pragma unroll
        for (int i = 0; i < 4; ++i) {
            gload16(aSrc[i], aDst[i]);
            gload16(bSrc[i], bDst[i]);
        }
        __syncthreads();
        #pragma unroll
        for (int kh = 0; kh < 2; ++kh) {
            bf16x8 af[4], bfv[4];
            const int sw = (((kh << 2) | g) ^ (c & 7)) << 3;
            #pragma unroll
            for (int mi = 0; mi < 4; ++mi)
                af[mi] = *(const bf16x8*)&sA[(wm * 64 + mi * 16 + c) * 64 + sw];
            #pragma unroll
            for (int ni = 0; ni < 4; ++ni)
                bfv[ni] = *(const bf16x8*)&sB[(wn * 64 + ni * 16 + c) * 64 + sw];
            #pragma unroll
            for (int mi = 0; mi < 4; ++mi)
                #pragma unroll
                for (int ni = 0; ni < 4; ++ni)
                    acc[mi][ni] = __builtin_amdgcn_mfma_f32_16x16x32_bf16(af[mi], bfv[ni], acc[mi][ni], 0, 0, 0);
        }
        #pragma unroll
        for (int i = 0; i < 4; ++i) { aSrc[i] += 64; bSrc[i] += 64; }
        __syncthreads();
    }

    if (MODE == 1) {
        #pragma unroll
        for (int mi = 0; mi < 4; ++mi)
            #pragma unroll
            for (int ni = 0; ni < 4; ++ni) {
                int n = col0 + wn * 64 + ni * 16 + c;
                float bias = b0[n];
                #pragma unroll
                for (int r = 0; r < 4; ++r)
                    Of[(size_t)(row0 + wm * 64 + mi * 16 + 4 * g + r) * 512 + n] =
                        acc[mi][ni][r] + bias;
            }
    } else {
        const int which = col0 >> 9;   // 0=Q 1=K 2=V
        const float* bias = which == 0 ? b0 : (which == 1 ? b1 : b2);
        ushort_t (*Cl)[136] = (ushort_t(*)[136])smem;
        if (which < 2) {
            #pragma unroll
            for (int mi = 0; mi < 4; ++mi)
                #pragma unroll
                for (int ni = 0; ni < 4; ++ni) {
                    int n = wn * 64 + ni * 16 + c;
                    float bb = bias[(col0 & 511) + n];
                    #pragma unroll
                    for (int r = 0; r < 4; ++r)
                        Cl[wm * 64 + mi * 16 + 4 * g + r][n] = f2bf(acc[mi][ni][r] + bb);
                }
        } else {
            #pragma unroll
            for (int mi = 0; mi < 4; ++mi)
                #pragma unroll
                for (int ni = 0; ni < 4; ++ni) {
                    int n = wn * 64 + ni * 16 + c;
                    float bb = bias[(col0 & 511) + n];
                    #pragma unroll
                    for (int r = 0; r < 4; ++r)
                        Cl[n][wm * 64 + mi * 16 + 4 * g + r] = f2bf(acc[mi][ni][r] + bb);
                }
        }
        __syncthreads();
        const int r = t >> 1, half = t & 1;
        const int b = row0 >> 11;
        if (which < 2) {
            ushort_t* Out = which == 0 ? O0 : O1;
            int s = (row0 & 2047) + r;
            int e = (col0 & 511) + half * 64;
            int h = e >> 6;
            ushort_t* dst = Out + (((size_t)(b * 8 + h) * 2048 + s) << 6);
            #pragma unroll
            for (int j = 0; j < 8; ++j)
                *(bf16x8*)(dst + j * 8) = *(const bf16x8*)&Cl[r][half * 64 + j * 8];
        } else {
            int e = (col0 & 511) + r;
            int h = e >> 6, d = e & 63;
            int s0 = (row0 & 2047) + half * 64;
            ushort_t* dst = O2 + ((size_t)(b * 8 + h) * 64 + d) * 2048 + s0;
            #pragma unroll
            for (int j = 0; j < 8; ++j)
                *(bf16x8*)(dst + j * 8) = *(const bf16x8*)&Cl[r][half * 64 + j * 8];
        }
    }
}

// ---------------------------------------------------------------------------
// Vsum[b,h,d] = sum_s V[b,h,s,d] from Vt rows (coalesced).
// ---------------------------------------------------------------------------
__global__ __launch_bounds__(256) void vsum2(
    const __hip_bfloat16* __restrict__ Vt, float* __restrict__ Vsum)
{
    const int row = blockIdx.x * 4 + (threadIdx.x >> 6);   // 0..2047 = bh*64+d
    const int l = threadIdx.x & 63;
    const unsigned short* p = (const unsigned short*)Vt + (size_t)row * S_;
    float s = 0.f;
    #pragma unroll
    for (int i = 0; i < 4; ++i) {
        uint4 u = *(const uint4*)(p + i * 512 + l * 8);
        s += bf2f((unsigned short)(u.x & 0xffff)) + bf2f((unsigned short)(u.x >> 16));
        s += bf2f((unsigned short)(u.y & 0xffff)) + bf2f((unsigned short)(u.y >> 16));
        s += bf2f((unsigned short)(u.z & 0xffff)) + bf2f((unsigned short)(u.z >> 16));
        s += bf2f((unsigned short)(u.w & 0xffff)) + bf2f((unsigned short)(u.w >> 16));
    }
    #pragma unroll
    for (int m = 1; m < 64; m <<= 1) s += __shfl_xor(s, m);
    if (l == 0) Vsum[row] = s;
}

// ---------------------------------------------------------------------------
// MFMA flash attention, round 9: 32x32x16 reg-P (r7) + 8B-granule swizzle
// (r8, 2-way = free) + 2 waves/SIMD TLP (r6's winning occupancy):
// 4 waves x 32 q = 128 q/block, grid 512 = 2 blocks/CU, launch_bounds(256,2).
// Reg-staged dbuf K/V (T14: loads at step top, swizzled b64 commits after PV).
// ---------------------------------------------------------------------------
__global__ __launch_bounds__(256, 2) void attn_mfma(
    const __hip_bfloat16* __restrict__ Qb, const __hip_bfloat16* __restrict__ Kb,
    const __hip_bfloat16* __restrict__ Vt, const float* __restrict__ Vsum,
    const float* __restrict__ dock, const int* __restrict__ mask,
    const float* __restrict__ mbg, const float* __restrict__ beta_p,
    ushort_t* __restrict__ ctxb)
{
    __shared__ __align__(16) unsigned char smem[32768];
    ushort_t* Kbuf = (ushort_t*)smem;                 // [2][64 rows][64] = 16 KB
    ushort_t* Vbuf = (ushort_t*)(smem + 16384);       // [2][64 rows][64] = 16 KB
    // epilogue alias: ushort [4][32][72] = 18432 B

    // XCD swizzle: 4 bh per XCD, 16 q-tiles (128 q) per bh. grid 512.
    const int flat = blockIdx.x;
    const int xcd = flat & 7, idx = flat >> 3;        // idx 0..63
    const int bh = ((idx >> 4) << 3) | xcd;
    const int qtile = idx & 15;
    const int b = bh >> 3, h8 = bh & 7;
    const int t = threadIdx.x, w = t >> 6, lam = t & 63;
    const int lq = lam & 31, hf = lam >> 5;
    const int q0 = qtile * 128 + w * 32;
    const int qg = q0 + lq;
    const float beta = beta_p[0];
    const ushort_t* Kp = (const ushort_t*)Kb + (size_t)bh * S_ * HD_;
    const ushort_t* Vp = (const ushort_t*)Vt + (size_t)bh * HD_ * S_;
    const float* mbp = mbg + b * S_;

    // staging thread geometry: row = t>>2 (0..63), quad = t&3; 8B granules
    const int srow = t >> 2, squad = t & 3;
    const int sx = ((srow & 7) << 1) | ((srow >> 3) & 1);
    int wof[4];
    #pragma unroll
    for (int i = 0; i < 4; ++i)
        wof[i] = srow * 64 + ((((squad << 2) | i) ^ sx) << 2);

    // frag-read swizzle (rows kt2*32+lq / dt*32+lq)
    const int xr = ((lq & 7) << 1) | ((lq >> 3) & 1);

    // Q fragments: qf[hd] = Q[qg][hd*16 + hf*8 + 0..7]
    bf16x8 qf[4];
    #pragma unroll
    for (int hd = 0; hd < 4; ++hd)
        qf[hd] = *(const bf16x8*)((const ushort_t*)Qb +
            ((size_t)bh * S_ + qg) * HD_ + hd * 16 + hf * 8);

    f32x16 cacc[2];
    cacc[0] = (f32x16)0.f;
    cacc[1] = (f32x16)0.f;
    float l_ = 0.f;
    const float CSC = 0.18033688011112042f;   // 0.125 * log2(e)

    // ---- prologue: stage tile 0 into par 0 ----
    {
        uint4 kg0 = *(const uint4*)(Kp + (size_t)srow * 64 + squad * 16);
        uint4 kg1 = *(const uint4*)(Kp + (size_t)srow * 64 + squad * 16 + 8);
        uint4 vg0 = *(const uint4*)(Vp + (size_t)srow * 2048 + squad * 16);
        uint4 vg1 = *(const uint4*)(Vp + (size_t)srow * 2048 + squad * 16 + 8);
        *(uint2*)(Kbuf + wof[0]) = make_uint2(kg0.x, kg0.y);
        *(uint2*)(Kbuf + wof[1]) = make_uint2(kg0.z, kg0.w);
        *(uint2*)(Kbuf + wof[2]) = make_uint2(kg1.x, kg1.y);
        *(uint2*)(Kbuf + wof[3]) = make_uint2(kg1.z, kg1.w);
        *(uint2*)(Vbuf + wof[0]) = make_uint2(vg0.x, vg0.y);
        *(uint2*)(Vbuf + wof[1]) = make_uint2(vg0.z, vg0.w);
        *(uint2*)(Vbuf + wof[2]) = make_uint2(vg1.x, vg1.y);
        *(uint2*)(Vbuf + wof[3]) = make_uint2(vg1.z, vg1.w);
    }
    __syncthreads();

    for (int k0 = 0; k0 < S_; k0 += 64) {
        const int par = (k0 >> 6) & 1;
        const ushort_t* KBp = Kbuf + par * 4096;
        const ushort_t* VBp = Vbuf + par * 4096;
        const bool pre = (k0 + 64 < S_);

        // (1) issue next-tile global loads — in flight under this step's compute
        uint4 kg0, kg1, vg0, vg1;
        if (pre) {
            kg0 = *(const uint4*)(Kp + (size_t)(k0 + 64 + srow) * 64 + squad * 16);
            kg1 = *(const uint4*)(Kp + (size_t)(k0 + 64 + srow) * 64 + squad * 16 + 8);
            vg0 = *(const uint4*)(Vp + (size_t)srow * 2048 + k0 + 64 + squad * 16);
            vg1 = *(const uint4*)(Vp + (size_t)srow * 2048 + k0 + 64 + squad * 16 + 8);
        }
        // (2) mask-bias for this step's 64 keys (L1-resident broadcast)
        float4 mb[2][4];
        #pragma unroll
        for (int kt2 = 0; kt2 < 2; ++kt2)
            #pragma unroll
            for (int qd = 0; qd < 4; ++qd)
                mb[kt2][qd] = *(const float4*)(mbp + k0 + kt2 * 32 + qd * 8 + hf * 4);

        // (3) QK^T: sacc[kt2] = D[key][q]
        f32x16 sacc[2];
        sacc[0] = (f32x16)0.f;
        sacc[1] = (f32x16)0.f;
        __builtin_amdgcn_s_setprio(1);
        #pragma unroll
        for (int kt2 = 0; kt2 < 2; ++kt2) {
            const ushort_t* kr = KBp + (kt2 * 32 + lq) * 64;
            #pragma unroll
            for (int hd = 0; hd < 4; ++hd) {
                uint2 lo = *(const uint2*)(kr + ((((hd << 2) | (hf << 1)) ^ xr) << 2));
                uint2 hi = *(const uint2*)(kr + ((((hd << 2) | (hf << 1) | 1) ^ xr) << 2));
                union { bf16x8 v; uint4 u; } kf;
                kf.u = make_uint4(lo.x, lo.y, hi.x, hi.y);
                sacc[kt2] = __builtin_amdgcn_mfma_f32_32x32x16_bf16(kf.v, qf[hd], sacc[kt2], 0, 0, 0);
            }
        }
        __builtin_amdgcn_s_setprio(0);

        // (4) softmax numerator (no max; scores provably tiny)
        float p[2][16];
        float ps = 0.f;
        #pragma unroll
        for (int kt2 = 0; kt2 < 2; ++kt2)
            #pragma unroll
            for (int qd = 0; qd < 4; ++qd) {
                float4 m4 = mb[kt2][qd];
                float p0 = EXP2F(fmaf(sacc[kt2][qd * 4 + 0], CSC, m4.x));
                float p1 = EXP2F(fmaf(sacc[kt2][qd * 4 + 1], CSC, m4.y));
                float p2 = EXP2F(fmaf(sacc[kt2][qd * 4 + 2], CSC, m4.z));
                float p3 = EXP2F(fmaf(sacc[kt2][qd * 4 + 3], CSC, m4.w));
                p[kt2][qd * 4 + 0] = p0; p[kt2][qd * 4 + 1] = p1;
                p[kt2][qd * 4 + 2] = p2; p[kt2][qd * 4 + 3] = p3;
                ps += p0 + p1 + p2 + p3;
            }
        l_ += ps;

        // (5) PV: B-frag = own p regs (phi), A-frag = V b64 pair
        __builtin_amdgcn_s_setprio(1);
        #pragma unroll
        for (int kt2 = 0; kt2 < 2; ++kt2)
            #pragma unroll
            for (int ks = 0; ks < 2; ++ks) {
                bf16x8 pf;
                #pragma unroll
                for (int m = 0; m < 8; ++m)
                    pf[m] = (short)f2bf(p[kt2][ks * 8 + m]);
                #pragma unroll
                for (int dt = 0; dt < 2; ++dt) {
                    const ushort_t* vr = VBp + (dt * 32 + lq) * 64;
                    uint2 lo = *(const uint2*)(vr + (((8 * kt2 + 4 * ks + hf) ^ xr) << 2));
                    uint2 hi = *(const uint2*)(vr + (((8 * kt2 + 4 * ks + 2 + hf) ^ xr) << 2));
                    union { bf16x8 v; uint4 u; } vf;
                    vf.u = make_uint4(lo.x, lo.y, hi.x, hi.y);
                    cacc[dt] = __builtin_amdgcn_mfma_f32_32x32x16_bf16(vf.v, pf, cacc[dt], 0, 0, 0);
                }
            }
        __builtin_amdgcn_s_setprio(0);

        // (6) commit next tile (compiler inserts vmcnt before first use)
        if (pre) {
            ushort_t* KD = Kbuf + (par ^ 1) * 4096;
            ushort_t* VD = Vbuf + (par ^ 1) * 4096;
            *(uint2*)(KD + wof[0]) = make_uint2(kg0.x, kg0.y);
            *(uint2*)(KD + wof[1]) = make_uint2(kg0.z, kg0.w);
            *(uint2*)(KD + wof[2]) = make_uint2(kg1.x, kg1.y);
            *(uint2*)(KD + wof[3]) = make_uint2(kg1.z, kg1.w);
            *(uint2*)(VD + wof[0]) = make_uint2(vg0.x, vg0.y);
            *(uint2*)(VD + wof[1]) = make_uint2(vg0.z, vg0.w);
            *(uint2*)(VD + wof[2]) = make_uint2(vg1.x, vg1.y);
            *(uint2*)(VD + wof[3]) = make_uint2(vg1.z, vg1.w);
        }
        __syncthreads();
    }

    // finalize l: complementary 16-key half lives in lane^32
    l_ += __shfl_xor(l_, 32);

    __syncthreads();   // staging buffers dead -> reuse as ctxl

    // ---- epilogue: blend + transpose via LDS (bf16), coalesced writes ----
    ushort_t* ctxl = (ushort_t*)smem;   // [4][32][72]
    {
        const float w1 = (1.f - beta) / l_;
        const float dq = (mask[b * S_ + qg] ? dock[b * S_ + qg] : 0.f) * beta;
        #pragma unroll
        for (int dt = 0; dt < 2; ++dt)
            #pragma unroll
            for (int qd = 0; qd < 4; ++qd) {
                const int d0 = dt * 32 + qd * 8 + hf * 4;
                float4 vs = *(const float4*)(Vsum + bh * 64 + d0);
                float o0 = cacc[dt][qd * 4 + 0] * w1 + dq * vs.x;
                float o1 = cacc[dt][qd * 4 + 1] * w1 + dq * vs.y;
                float o2 = cacc[dt][qd * 4 + 2] * w1 + dq * vs.z;
                float o3 = cacc[dt][qd * 4 + 3] * w1 + dq * vs.w;
                uint lo = (uint)f2bf(o0) | ((uint)f2bf(o1) << 16);
                uint hi = (uint)f2bf(o2) | ((uint)f2bf(o3) << 16);
                *(uint2*)(ctxl + (size_t)w * 2304 + lq * 72 + d0) = make_uint2(lo, hi);
            }
    }
    __syncthreads();
    {
        const int qloc = lam >> 1, half = lam & 1;
        ushort_t* cp = ctxb + ((size_t)(b * 2048 + q0 + qloc)) * 512 + h8 * 64 + half * 32;
        const ushort_t* rp = ctxl + (size_t)w * 2304 + qloc * 72 + half * 32;
        #pragma unroll
        for (int j = 0; j < 4; ++j)
            *(bf16x8*)(cp + j * 8) = *(const bf16x8*)(rp + j * 8);
    }
}

extern "C" void kernel_launch(void* const* d_in, const int* in_sizes, int n_in,
                              void* d_out, int out_size, void* d_ws, size_t ws_size,
                              hipStream_t stream)
{
    const float* x    = (const float*)d_in[0];
    const float* dock = (const float*)d_in[1];
    const int*   mask = (const int*)d_in[2];
    const float* Wq   = (const float*)d_in[3];
    const float* bq   = (const float*)d_in[4];
    const float* Wk   = (const float*)d_in[5];
    const float* bk   = (const float*)d_in[6];
    const float* Wv   = (const float*)d_in[7];
    const float* bv   = (const float*)d_in[8];
    const float* Wo   = (const float*)d_in[9];
    const float* bo   = (const float*)d_in[10];
    const float* beta = (const float*)d_in[12];   // alpha = d_in[11] unused
    float* out = (float*)d_out;

    const size_t nqkv = (size_t)B_ * H_ * S_ * HD_;   // 4,194,304 elems
    ushort_t* xb    = (ushort_t*)d_ws;                // 8 MB (reused as ctxb)
    ushort_t* Qb    = xb + nqkv;                      // 8 MB
    ushort_t* Kb    = Qb + nqkv;                      // 8 MB
    ushort_t* Vt    = Kb + nqkv;                      // 8 MB (B,H,HD,S)
    ushort_t* Wqkvb = Vt + nqkv;                      // 1.5 MB  [1536][512]
    ushort_t* Wob   = Wqkvb + 1536 * 512;             // 0.5 MB  [512][512]
    float*    Vsum  = (float*)(Wob + 512 * 512);      // 8 KB
    float*    mbg   = Vsum + 2048;                    // 32 KB mask-bias
    ushort_t* ctxb  = xb;                             // alias (x consumed by then)

    convert_all<<<1280, 256, 0, stream>>>(x, Wq, Wk, Wv, Wo, mask, xb, Wqkvb, Wob, mbg);
    gemm_mfma<0><<<dim3(12, 64), 256, 0, stream>>>(xb, Wqkvb, bq, bk, bv, Qb, Kb, Vt, nullptr);
    vsum2<<<512, 256, 0, stream>>>((const __hip_bfloat16*)Vt, Vsum);
    attn_mfma<<<512, 256, 0, stream>>>(
        (const __hip_bfloat16*)Qb, (const __hip_bfloat16*)Kb, (const __hip_bfloat16*)Vt,
        Vsum, dock, mask, mbg, beta, ctxb);
    gemm_mfma<1><<<dim3(4, 64), 256, 0, stream>>>(ctxb, Wob, bo, nullptr, nullptr,
                                                  nullptr, nullptr, nullptr, out);
}